// Round 8
// baseline (424.040 us; speedup 1.0000x reference)
//
#include <hip/hip_runtime.h>
#include <hip/hip_cooperative_groups.h>

namespace cg = cooperative_groups;

// Problem constants
#define GPART 4
// 1/sqrt(32), folded into Wq at conversion time:
#define INV_SCALE 0.17677669529663687f
#define SMEM_SZ 36864

typedef __attribute__((ext_vector_type(8))) short bf16x8;
typedef __attribute__((ext_vector_type(4))) float f32x4;

__device__ __forceinline__ unsigned int pk2bf(float a, float b) {
  unsigned int ua = __float_as_uint(a);
  ua = (ua + 0x7FFFu + ((ua >> 16) & 1u)) >> 16;
  unsigned int ub = __float_as_uint(b);
  ub = (ub + 0x7FFFu + ((ub >> 16) & 1u)) >> 16;
  return ua | (ub << 16);
}
__device__ __forceinline__ ushort cv1(float f) {
  unsigned int u = __float_as_uint(f);
  return (ushort)((u + 0x7FFFu + ((u >> 16) & 1u)) >> 16);
}
__device__ __forceinline__ unsigned int pkfast(float a, float b) {
  unsigned int au = __float_as_uint(a) + 0x8000u;
  unsigned int bu = __float_as_uint(b) + 0x8000u;
  return __builtin_amdgcn_perm(bu, au, 0x07060302u);
}
__device__ __forceinline__ float bf2f(ushort v) {
  return __uint_as_float((unsigned int)v << 16);
}

// ---------------------------------------------------------------------------
// Phase 1a: MFMA Q/K projection -> bf16. bid -> (b = bid>>7, nt-tile = bid&127)
// ---------------------------------------------------------------------------
__device__ void ph_proj(const float* x, const float* Wq, const float* Wk,
                        ushort* Qb, ushort* Kb, char* smem, int bid) {
  float* xl = (float*)smem;  // 128*66 floats = 33792 B
  const int b = bid >> 7;
  const int nt0 = (bid & 127) * 64;
  const int nq = nt0 >> 4;
  const int tid = threadIdx.x;
  const int w = tid >> 6, lane = tid & 63;
  const int lm = lane & 15, quad = lane >> 4;

  const float* xb = x + (size_t)b * 1048576 + nt0;
#pragma unroll
  for (int L = tid * 4; L < 8192; L += 1024) {
    int c = L >> 6, j = L & 63;
    float4 v = *(const float4*)(xb + c * 8192 + j);
    float2* dp = (float2*)(xl + c * 66 + j);
    dp[0] = make_float2(v.x, v.y);
    dp[1] = make_float2(v.z, v.w);
  }

  const int o0 = w * 32;
  bf16x8 aq[2][4], ak[2][4];
#pragma unroll
  for (int ot = 0; ot < 2; ++ot)
#pragma unroll
    for (int kc = 0; kc < 4; ++kc) {
      const int off = (o0 + ot * 16 + lm) * 128 + kc * 32 + quad * 8;
      const float4 q1 = *(const float4*)(Wq + off);
      const float4 q2 = *(const float4*)(Wq + off + 4);
      const float4 k1 = *(const float4*)(Wk + off);
      const float4 k2 = *(const float4*)(Wk + off + 4);
      union { uint4 u; bf16x8 v; } cq, ck;
      cq.u.x = pk2bf(q1.x * INV_SCALE, q1.y * INV_SCALE);
      cq.u.y = pk2bf(q1.z * INV_SCALE, q1.w * INV_SCALE);
      cq.u.z = pk2bf(q2.x * INV_SCALE, q2.y * INV_SCALE);
      cq.u.w = pk2bf(q2.z * INV_SCALE, q2.w * INV_SCALE);
      ck.u.x = pk2bf(k1.x, k1.y);
      ck.u.y = pk2bf(k1.z, k1.w);
      ck.u.z = pk2bf(k2.x, k2.y);
      ck.u.w = pk2bf(k2.z, k2.w);
      aq[ot][kc] = cq.v;
      ak[ot][kc] = ck.v;
    }
  __syncthreads();

#pragma unroll
  for (int jtl = 0; jtl < 4; ++jtl) {
    bf16x8 bfr[4];
#pragma unroll
    for (int kc = 0; kc < 4; ++kc) {
      const float* sp = xl + (kc * 32 + quad * 8) * 66 + jtl * 16 + lm;
      float f0 = sp[0],   f1 = sp[66],  f2 = sp[132], f3 = sp[198];
      float f4 = sp[264], f5 = sp[330], f6 = sp[396], f7 = sp[462];
      union { uint4 u; bf16x8 v; } cv;
      cv.u.x = pkfast(f0, f1);
      cv.u.y = pkfast(f2, f3);
      cv.u.z = pkfast(f4, f5);
      cv.u.w = pkfast(f6, f7);
      bfr[kc] = cv.v;
    }

    f32x4 accq0 = {0,0,0,0}, accq1 = {0,0,0,0};
    f32x4 acck0 = {0,0,0,0}, acck1 = {0,0,0,0};
#pragma unroll
    for (int kc = 0; kc < 4; ++kc) {
      accq0 = __builtin_amdgcn_mfma_f32_16x16x32_bf16(aq[0][kc], bfr[kc], accq0, 0, 0, 0);
      accq1 = __builtin_amdgcn_mfma_f32_16x16x32_bf16(aq[1][kc], bfr[kc], accq1, 0, 0, 0);
      acck0 = __builtin_amdgcn_mfma_f32_16x16x32_bf16(ak[0][kc], bfr[kc], acck0, 0, 0, 0);
      acck1 = __builtin_amdgcn_mfma_f32_16x16x32_bf16(ak[1][kc], bfr[kc], acck1, 0, 0, 0);
    }

    const size_t base = (size_t)b * 1048576 + (size_t)lm * 65536 + w * 16384 +
                        (size_t)(nq + jtl) * 32 + quad * 4;
    uint2 uq0, uq1, uk0, uk1;
    uq0.x = pk2bf(accq0[0], accq0[1]); uq0.y = pk2bf(accq0[2], accq0[3]);
    uq1.x = pk2bf(accq1[0], accq1[1]); uq1.y = pk2bf(accq1[2], accq1[3]);
    uk0.x = pk2bf(acck0[0], acck0[1]); uk0.y = pk2bf(acck0[2], acck0[3]);
    uk1.x = pk2bf(acck1[0], acck1[1]); uk1.y = pk2bf(acck1[2], acck1[3]);
    *(uint2*)(Qb + base)      = uq0;
    *(uint2*)(Qb + base + 16) = uq1;
    *(uint2*)(Kb + base)      = uk0;
    *(uint2*)(Kb + base + 16) = uk1;
  }
}

// ---------------------------------------------------------------------------
// Block reductions (small shared scratch passed in)
// ---------------------------------------------------------------------------
__device__ __forceinline__ float blk_max(float v, float* red, int tid) {
#pragma unroll
  for (int off = 32; off > 0; off >>= 1) v = fmaxf(v, __shfl_xor(v, off, 64));
  if ((tid & 63) == 0) red[tid >> 6] = v;
  __syncthreads();
  v = fmaxf(fmaxf(red[0], red[1]), fmaxf(red[2], red[3]));
  __syncthreads();
  return v;
}
__device__ __forceinline__ float blk_sum(float v, float* red, int tid) {
#pragma unroll
  for (int off = 32; off > 0; off >>= 1) v += __shfl_xor(v, off, 64);
  if ((tid & 63) == 0) red[tid >> 6] = v;
  __syncthreads();
  v = (red[0] + red[1]) + (red[2] + red[3]);
  __syncthreads();
  return v;
}

// Phase 1b: att_struct = softmax(structural, axis=-1); row i = bid
__device__ void ph_struct(const float* S, float* st, char* smem, int bid) {
  float* red = (float*)(smem + 34816);  // beyond xl
  const int i = bid, tid = threadIdx.x;
  float s0 = S[i * 512 + tid], s1 = S[i * 512 + tid + 256];
  float m = blk_max(fmaxf(s0, s1), red, tid);
  float e0 = __expf(s0 - m), e1 = __expf(s1 - m);
  float sum = blk_sum(e0 + e1, red, tid);
  float inv = 1.0f / sum;
  st[i * 512 + tid] = e0 * inv;
  st[i * 512 + tid + 256] = e1 * inv;
}

// ---------------------------------------------------------------------------
// Phase 2: MFMA scores + softmax + partial mean. bid -> (strip=bid&31,
// g=(bid>>5)&3, b=bid>>7); 16 (t,h) pairs per block, GPART=4.
// ---------------------------------------------------------------------------
__device__ void ph_scores(const ushort* Qb, const ushort* Kb, ushort* part,
                          char* smem, int bid) {
  float* SH = (float*)smem;                         // 16*516 = 33024 B
  float (*red)[4][16] = (float(*)[4][16])(smem + 33024);  // 512 B
  const int strip = bid & 31, g = (bid >> 5) & 3, b = bid >> 7;
  const int tid = threadIdx.x;
  const int w = tid >> 6, lane = tid & 63;
  const int lm = lane & 15, quad = lane >> 4;
  const int n0 = strip * 16;
  const int wcol0 = w * 128;

  float acc[32];
#pragma unroll
  for (int i = 0; i < 32; ++i) acc[i] = 0.f;

  for (int pi = 0; pi < 16; ++pi) {
    const int p = g * 16 + pi;
    const size_t base = (size_t)((b * 16 + (p >> 2)) * 4 + (p & 3)) * 16384;
    bf16x8 afrag = *(const bf16x8*)(Qb + base + (size_t)(n0 + lm) * 32 + quad * 8);
    bf16x8 bfr[8];
#pragma unroll
    for (int ct = 0; ct < 8; ++ct)
      bfr[ct] = *(const bf16x8*)(Kb + base + (size_t)(wcol0 + ct * 16 + lm) * 32 + quad * 8);

    f32x4 d[8];
#pragma unroll
    for (int ct = 0; ct < 8; ++ct) {
      f32x4 z = {0.f, 0.f, 0.f, 0.f};
      d[ct] = __builtin_amdgcn_mfma_f32_16x16x32_bf16(afrag, bfr[ct], z, 0, 0, 0);
    }

    float cur[32];
    float rp0 = 0.f, rp1 = 0.f, rp2 = 0.f, rp3 = 0.f;
#pragma unroll
    for (int ct = 0; ct < 8; ++ct) {
      float e0 = __expf(d[ct][0]);
      float e1 = __expf(d[ct][1]);
      float e2 = __expf(d[ct][2]);
      float e3 = __expf(d[ct][3]);
      cur[ct * 4 + 0] = e0; cur[ct * 4 + 1] = e1;
      cur[ct * 4 + 2] = e2; cur[ct * 4 + 3] = e3;
      rp0 += e0; rp1 += e1; rp2 += e2; rp3 += e3;
    }
#pragma unroll
    for (int m = 1; m < 16; m <<= 1) {
      rp0 += __shfl_xor(rp0, m);
      rp1 += __shfl_xor(rp1, m);
      rp2 += __shfl_xor(rp2, m);
      rp3 += __shfl_xor(rp3, m);
    }
    if (lm == 0) {
      red[pi & 1][w][quad * 4 + 0] = rp0;
      red[pi & 1][w][quad * 4 + 1] = rp1;
      red[pi & 1][w][quad * 4 + 2] = rp2;
      red[pi & 1][w][quad * 4 + 3] = rp3;
    }
    __syncthreads();
#pragma unroll
    for (int r = 0; r < 4; ++r) {
      float rs = red[pi & 1][0][quad * 4 + r] + red[pi & 1][1][quad * 4 + r] +
                 red[pi & 1][2][quad * 4 + r] + red[pi & 1][3][quad * 4 + r];
      float inv = 1.0f / rs;
#pragma unroll
      for (int ct = 0; ct < 8; ++ct)
        acc[ct * 4 + r] = fmaf(cur[ct * 4 + r], inv, acc[ct * 4 + r]);
    }
  }

#pragma unroll
  for (int ct = 0; ct < 8; ++ct) {
#pragma unroll
    for (int r = 0; r < 4; ++r)
      SH[(quad * 4 + r) * 516 + wcol0 + ct * 16 + lm] = acc[ct * 4 + r];
  }
  __syncthreads();
  const int row = tid >> 4, colb = (tid & 15) * 4;
  ushort* po = part + ((size_t)((g * 4 + b) * 512 + n0 + row)) * 512 + colb;
#pragma unroll
  for (int k = 0; k < 8; ++k) {
    f32x4 v = *(const f32x4*)(SH + row * 516 + colb + k * 64);
    uint2 u;
    u.x = pk2bf(v[0], v[1]);
    u.y = pk2bf(v[2], v[3]);
    *(uint2*)(po + k * 64) = u;
  }
}

// ---------------------------------------------------------------------------
// Phase 3a: x[b,c,j,t] fp32 -> xtb[b,c,t,j] bf16. bid -> (c=bid&127, b=bid>>7)
// ---------------------------------------------------------------------------
__device__ void ph_xconv(const float* x, ushort* xtb, char* smem, int bid) {
  ushort* xs = (ushort*)smem;  // 16*520*2 = 16640 B
  const int c = bid & 127, b = bid >> 7;
  const int tid = threadIdx.x;
  const float* in = x + ((size_t)b * 128 + c) * 8192;
  ushort* outp = xtb + ((size_t)b * 128 + c) * 8192;

#pragma unroll
  for (int it = 0; it < 8; ++it) {
    int idx = (tid + it * 256) * 4;
    int j = idx >> 4, t0 = idx & 15;
    float4 v = *(const float4*)(in + idx);
    xs[(t0 + 0) * 520 + j] = cv1(v.x);
    xs[(t0 + 1) * 520 + j] = cv1(v.y);
    xs[(t0 + 2) * 520 + j] = cv1(v.z);
    xs[(t0 + 3) * 520 + j] = cv1(v.w);
  }
  __syncthreads();
#pragma unroll
  for (int it = 0; it < 4; ++it) {
    int u = (tid + it * 256) * 8;
    int t = u >> 9, j0 = u & 511;
    *(uint4*)(outp + u) = *(const uint4*)(xs + t * 520 + j0);
  }
}

// ---------------------------------------------------------------------------
// Phase 3b: reduce GPART partials AND symmetrize. unit = bid (0..179):
// z = bid/36 (0..3 accA-b, 4 = st in place), tile-pair = bid%36.
// ---------------------------------------------------------------------------
__device__ void ph_redsym(const ushort* part, float* Ssym, float* st,
                          char* smem, int bid) {
  float* L1 = (float*)smem;          // 64*68*4 = 17408
  float* L2 = L1 + 64 * 68;          // 17408
  const int z = bid / 36;
  int rem = bid % 36, ti = 0;
  for (;;) { int cnt = 8 - ti; if (rem < cnt) break; rem -= cnt; ++ti; }
  const int tj = ti + rem;
  const bool diag = (ti == tj);
  const int tid = threadIdx.x;
  const int rr = tid >> 2, cc = (tid & 3) * 16;

  float a1[16], a2[16];
#pragma unroll
  for (int k = 0; k < 16; ++k) { a1[k] = 0.f; a2[k] = 0.f; }

  if (z == 4) {
    const float* p1 = st + (ti * 64 + rr) * 512 + tj * 64 + cc;
    const float* p2 = st + (tj * 64 + rr) * 512 + ti * 64 + cc;
#pragma unroll
    for (int q = 0; q < 4; ++q) {
      float4 v = *(const float4*)(p1 + q * 4);
      a1[q * 4 + 0] = v.x; a1[q * 4 + 1] = v.y;
      a1[q * 4 + 2] = v.z; a1[q * 4 + 3] = v.w;
      if (!diag) {
        float4 u = *(const float4*)(p2 + q * 4);
        a2[q * 4 + 0] = u.x; a2[q * 4 + 1] = u.y;
        a2[q * 4 + 2] = u.z; a2[q * 4 + 3] = u.w;
      }
    }
  } else {
    const int b = z;
#pragma unroll
    for (int g = 0; g < GPART; ++g) {
      const ushort* p1 = part + ((size_t)((g * 4 + b) * 512 + ti * 64 + rr)) * 512 + tj * 64 + cc;
      const ushort* p2 = part + ((size_t)((g * 4 + b) * 512 + tj * 64 + rr)) * 512 + ti * 64 + cc;
#pragma unroll
      for (int q = 0; q < 4; ++q) {
        ushort4 v = *(const ushort4*)(p1 + q * 4);
        a1[q * 4 + 0] += bf2f(v.x); a1[q * 4 + 1] += bf2f(v.y);
        a1[q * 4 + 2] += bf2f(v.z); a1[q * 4 + 3] += bf2f(v.w);
        if (!diag) {
          ushort4 u = *(const ushort4*)(p2 + q * 4);
          a2[q * 4 + 0] += bf2f(u.x); a2[q * 4 + 1] += bf2f(u.y);
          a2[q * 4 + 2] += bf2f(u.z); a2[q * 4 + 3] += bf2f(u.w);
        }
      }
    }
  }

#pragma unroll
  for (int q = 0; q < 4; ++q) {
    *(float4*)(L1 + rr * 68 + cc + q * 4) =
        make_float4(a1[q * 4], a1[q * 4 + 1], a1[q * 4 + 2], a1[q * 4 + 3]);
    if (!diag)
      *(float4*)(L2 + rr * 68 + cc + q * 4) =
          make_float4(a2[q * 4], a2[q * 4 + 1], a2[q * 4 + 2], a2[q * 4 + 3]);
  }
  __syncthreads();

  float* M = (z < 4) ? (Ssym + (size_t)z * 262144) : st;
  const float* LT = diag ? L1 : L2;
#pragma unroll
  for (int q = 0; q < 4; ++q) {
    const int c = cc + q * 4;
    float4 o;
    o.x = L1[rr * 68 + c + 0] + LT[(c + 0) * 68 + rr];
    o.y = L1[rr * 68 + c + 1] + LT[(c + 1) * 68 + rr];
    o.z = L1[rr * 68 + c + 2] + LT[(c + 2) * 68 + rr];
    o.w = L1[rr * 68 + c + 3] + LT[(c + 3) * 68 + rr];
    *(float4*)(M + (ti * 64 + rr) * 512 + tj * 64 + c) = o;
  }
  if (!diag) {
#pragma unroll
    for (int q = 0; q < 4; ++q) {
      const int c = cc + q * 4;
      float4 o;
      o.x = L2[rr * 68 + c + 0] + L1[(c + 0) * 68 + rr];
      o.y = L2[rr * 68 + c + 1] + L1[(c + 1) * 68 + rr];
      o.z = L2[rr * 68 + c + 2] + L1[(c + 2) * 68 + rr];
      o.w = L2[rr * 68 + c + 3] + L1[(c + 3) * 68 + rr];
      *(float4*)(M + (tj * 64 + rr) * 512 + ti * 64 + c) = o;
    }
  }
}

// ---------------------------------------------------------------------------
// Phase 4: fused row softmax -> bf16. bid = i; loop over b.
// ---------------------------------------------------------------------------
__device__ void ph_fused(const float* Ssym, const float* st, const float* fw,
                         const float* fb, ushort* fusedb, char* smem, int bid) {
  float* red = (float*)smem;
  const int i = bid, tid = threadIdx.x;
  const float w0s = fw[0] * (0.5f / 64.f);
  const float w1s = fw[1] * 0.5f;
  const float bias = fb[0];
  const float* S = st + (size_t)i * 512;
  float2 s2 = *(const float2*)(S + tid * 2);
  for (int b = 0; b < 4; ++b) {
    const float* A = Ssym + (size_t)b * 262144 + (size_t)i * 512;
    float2 a2 = *(const float2*)(A + tid * 2);
    float l0 = fmaf(w0s, a2.x, fmaf(w1s, s2.x, bias));
    float l1 = fmaf(w0s, a2.y, fmaf(w1s, s2.y, bias));
    float m = blk_max(fmaxf(l0, l1), red, tid);
    float e0 = __expf(l0 - m), e1 = __expf(l1 - m);
    float sum = blk_sum(e0 + e1, red, tid);
    float inv = 1.0f / sum;
    *(unsigned int*)(fusedb + ((size_t)(b * 512 + i)) * 512 + tid * 2) =
        pk2bf(e0 * inv, e1 * inv);
  }
}

// ---------------------------------------------------------------------------
// Phase 5: MFMA aggregation. bid -> (cg=bid&15, i0=((bid>>4)&7)*64, b=bid>>7)
// ---------------------------------------------------------------------------
__device__ void ph_agg(const ushort* fusedb, const ushort* xtb, float* out,
                       char* smem, int bid) {
  ushort* xs = (ushort*)smem;
  const int cg = bid & 15;
  const int i0 = ((bid >> 4) & 7) * 64;
  const int b = bid >> 7;
  const int tid = threadIdx.x, w = tid >> 6, lane = tid & 63;
  const int lm = lane & 15, quad = lane >> 4;

  const ushort* fr = fusedb + ((size_t)(b * 512 + i0 + w * 16 + lm)) * 512 + quad * 8;
  bf16x8 af[16];
#pragma unroll
  for (int kk = 0; kk < 16; ++kk) af[kk] = *(const bf16x8*)(fr + kk * 32);

  const ushort* xg = xtb + ((size_t)b * 128 + cg * 8) * 8192;
  uint4 rg[4];
#pragma unroll
  for (int it = 0; it < 4; ++it) rg[it] = *(const uint4*)(xg + (tid + it * 256) * 8);

  for (int c = 0; c < 8; ++c) {
#pragma unroll
    for (int it = 0; it < 4; ++it) {
      int u = (tid + it * 256) * 8;
      int t = u >> 9, j0 = u & 511;
      *(uint4*)(xs + t * 520 + j0) = rg[it];
    }
    __syncthreads();
    if (c < 7) {
      const ushort* xg2 = xg + (size_t)(c + 1) * 8192;
#pragma unroll
      for (int it = 0; it < 4; ++it) rg[it] = *(const uint4*)(xg2 + (tid + it * 256) * 8);
    }
    f32x4 acc = {0.f, 0.f, 0.f, 0.f};
#pragma unroll
    for (int kk = 0; kk < 16; ++kk) {
      bf16x8 bf = *(const bf16x8*)(xs + lm * 520 + kk * 32 + quad * 8);
      acc = __builtin_amdgcn_mfma_f32_16x16x32_bf16(af[kk], bf, acc, 0, 0, 0);
    }
    float* op = out + (size_t)b * 1048576 + (size_t)(cg * 8 + c) * 8192 +
                (size_t)(i0 + w * 16 + quad * 4) * 16 + lm;
    op[0]  = acc[0];
    op[16] = acc[1];
    op[32] = acc[2];
    op[48] = acc[3];
    __syncthreads();
  }
}

// ---------------------------------------------------------------------------
// Mega cooperative kernel: all phases, grid 512 x 256.
// ---------------------------------------------------------------------------
__global__ __launch_bounds__(256, 2) void k_mega(const float* x, const float* Wq,
                                                 const float* Wk, const float* S,
                                                 const float* fw, const float* fb,
                                                 float* out, ushort* Qb, ushort* Kb,
                                                 ushort* part, ushort* xtb,
                                                 float* Ssym, float* st,
                                                 ushort* fusedb) {
  __shared__ __align__(16) char smem[SMEM_SZ];
  const int bid = blockIdx.x;
  cg::grid_group grid = cg::this_grid();

  ph_proj(x, Wq, Wk, Qb, Kb, smem, bid);
  ph_struct(S, st, smem, bid);
  grid.sync();
  ph_scores(Qb, Kb, part, smem, bid);
  grid.sync();
  ph_xconv(x, xtb, smem, bid);   // xtb overlays Qb (dead after phase 2)
  __syncthreads();
  if (bid < 180) ph_redsym(part, Ssym, st, smem, bid);
  grid.sync();
  ph_fused(Ssym, st, fw, fb, fusedb, smem, bid);
  grid.sync();
  ph_agg(fusedb, xtb, out, smem, bid);
}

// ---------------------------------------------------------------------------
// Fallback phase wrappers (used only if cooperative launch is unavailable)
// ---------------------------------------------------------------------------
__global__ __launch_bounds__(256, 2) void k_ph1(const float* x, const float* Wq,
                                                const float* Wk, const float* S,
                                                ushort* Qb, ushort* Kb, float* st) {
  __shared__ __align__(16) char smem[SMEM_SZ];
  ph_proj(x, Wq, Wk, Qb, Kb, smem, blockIdx.x);
  ph_struct(S, st, smem, blockIdx.x);
}
__global__ __launch_bounds__(256, 2) void k_ph2(const ushort* Qb, const ushort* Kb,
                                                ushort* part) {
  __shared__ __align__(16) char smem[SMEM_SZ];
  ph_scores(Qb, Kb, part, smem, blockIdx.x);
}
__global__ __launch_bounds__(256, 2) void k_ph3(const float* x, ushort* xtb,
                                                const ushort* part, float* Ssym,
                                                float* st) {
  __shared__ __align__(16) char smem[SMEM_SZ];
  ph_xconv(x, xtb, smem, blockIdx.x);
  __syncthreads();
  if (blockIdx.x < 180) ph_redsym(part, Ssym, st, smem, blockIdx.x);
}
__global__ __launch_bounds__(256, 2) void k_ph4(const float* Ssym, const float* st,
                                                const float* fw, const float* fb,
                                                ushort* fusedb) {
  __shared__ __align__(16) char smem[SMEM_SZ];
  ph_fused(Ssym, st, fw, fb, fusedb, smem, blockIdx.x);
}
__global__ __launch_bounds__(256, 2) void k_ph5(const ushort* fusedb,
                                                const ushort* xtb, float* out) {
  __shared__ __align__(16) char smem[SMEM_SZ];
  ph_agg(fusedb, xtb, out, smem, blockIdx.x);
}

// ---------------------------------------------------------------------------
extern "C" void kernel_launch(void* const* d_in, const int* in_sizes, int n_in,
                              void* d_out, int out_size, void* d_ws, size_t ws_size,
                              hipStream_t stream) {
  const float* x  = (const float*)d_in[0];
  const float* Wq = (const float*)d_in[1];
  const float* Wk = (const float*)d_in[2];
  const float* S  = (const float*)d_in[3];
  const float* fw = (const float*)d_in[4];
  const float* fb = (const float*)d_in[5];
  float* out = (float*)d_out;

  // workspace (31 MB): Qb 8 | Kb 8 | part 8 | Ssym 4 | st 1 | fusedb 2
  // xtb overlays Qb (written phase 3, after Qb's last read in phase 2)
  ushort* Qb   = (ushort*)d_ws;
  ushort* Kb   = Qb + 4194304;
  ushort* part = Kb + 4194304;     // GPART(4) x 4 b x 512 x 512 bf16 = 8 MB
  ushort* xtb  = Qb;               // overlay
  float* Ssym  = (float*)(part + 4194304);
  float* st    = Ssym + 1048576;
  ushort* fusedb = (ushort*)(st + 262144);

  void* args[] = {(void*)&x, (void*)&Wq, (void*)&Wk, (void*)&S, (void*)&fw,
                  (void*)&fb, (void*)&out, (void*)&Qb, (void*)&Kb, (void*)&part,
                  (void*)&xtb, (void*)&Ssym, (void*)&st, (void*)&fusedb};
  hipError_t e = hipLaunchCooperativeKernel((const void*)k_mega, dim3(512),
                                            dim3(256), args, 0, stream);
  if (e != hipSuccess) {
    // deterministic fallback: same phases as separate launches
    k_ph1<<<dim3(512), 256, 0, stream>>>(x, Wq, Wk, S, Qb, Kb, st);
    k_ph2<<<dim3(512), 256, 0, stream>>>(Qb, Kb, part);
    k_ph3<<<dim3(512), 256, 0, stream>>>(x, xtb, part, Ssym, st);
    k_ph4<<<dim3(512), 256, 0, stream>>>(Ssym, st, fw, fb, fusedb);
    k_ph5<<<dim3(512), 256, 0, stream>>>(fusedb, xtb, out);
  }
}

// Round 9
// 163.612 us; speedup vs baseline: 2.5917x; 2.5917x over previous
//
#include <hip/hip_runtime.h>

// Problem constants
#define GPART 8
// 1/sqrt(32), folded into Wq at conversion time:
#define INV_SCALE 0.17677669529663687f
#define SMEM_SZ 36864

typedef __attribute__((ext_vector_type(8))) short bf16x8;
typedef __attribute__((ext_vector_type(4))) float f32x4;

__device__ __forceinline__ unsigned int pk2bf(float a, float b) {
  unsigned int ua = __float_as_uint(a);
  ua = (ua + 0x7FFFu + ((ua >> 16) & 1u)) >> 16;
  unsigned int ub = __float_as_uint(b);
  ub = (ub + 0x7FFFu + ((ub >> 16) & 1u)) >> 16;
  return ua | (ub << 16);
}
__device__ __forceinline__ ushort cv1(float f) {
  unsigned int u = __float_as_uint(f);
  return (ushort)((u + 0x7FFFu + ((u >> 16) & 1u)) >> 16);
}
__device__ __forceinline__ unsigned int pkfast(float a, float b) {
  unsigned int au = __float_as_uint(a) + 0x8000u;
  unsigned int bu = __float_as_uint(b) + 0x8000u;
  return __builtin_amdgcn_perm(bu, au, 0x07060302u);
}
__device__ __forceinline__ float bf2f(ushort v) {
  return __uint_as_float((unsigned int)v << 16);
}

__device__ __forceinline__ float blk_max(float v, float* red, int tid) {
#pragma unroll
  for (int off = 32; off > 0; off >>= 1) v = fmaxf(v, __shfl_xor(v, off, 64));
  if ((tid & 63) == 0) red[tid >> 6] = v;
  __syncthreads();
  v = fmaxf(fmaxf(red[0], red[1]), fmaxf(red[2], red[3]));
  __syncthreads();
  return v;
}
__device__ __forceinline__ float blk_sum(float v, float* red, int tid) {
#pragma unroll
  for (int off = 32; off > 0; off >>= 1) v += __shfl_xor(v, off, 64);
  if ((tid & 63) == 0) red[tid >> 6] = v;
  __syncthreads();
  v = (red[0] + red[1]) + (red[2] + red[3]);
  __syncthreads();
  return v;
}

// ---------------------------------------------------------------------------
// Dispatch 1: MFMA Q/K projection -> bf16, fused with structural softmax.
// bid -> (b = bid>>7, nt-tile = bid&127); struct row i = bid.
// ---------------------------------------------------------------------------
__global__ __launch_bounds__(256) void k_ph1(const float* __restrict__ x,
                                             const float* __restrict__ Wq,
                                             const float* __restrict__ Wk,
                                             const float* __restrict__ S,
                                             ushort* __restrict__ Qb,
                                             ushort* __restrict__ Kb,
                                             float* __restrict__ st) {
  __shared__ __align__(16) char smem[SMEM_SZ];
  float* xl = (float*)smem;  // 128*66 floats = 33792 B
  const int bid = blockIdx.x;
  const int b = bid >> 7;
  const int nt0 = (bid & 127) * 64;
  const int nq = nt0 >> 4;
  const int tid = threadIdx.x;
  const int w = tid >> 6, lane = tid & 63;
  const int lm = lane & 15, quad = lane >> 4;

  // stage x[b][c][nt0..+63]
  const float* xb = x + (size_t)b * 1048576 + nt0;
#pragma unroll
  for (int L = tid * 4; L < 8192; L += 1024) {
    int c = L >> 6, j = L & 63;
    float4 v = *(const float4*)(xb + c * 8192 + j);
    float2* dp = (float2*)(xl + c * 66 + j);
    dp[0] = make_float2(v.x, v.y);
    dp[1] = make_float2(v.z, v.w);
  }

  const int o0 = w * 32;
  bf16x8 aq[2][4], ak[2][4];
#pragma unroll
  for (int ot = 0; ot < 2; ++ot)
#pragma unroll
    for (int kc = 0; kc < 4; ++kc) {
      const int off = (o0 + ot * 16 + lm) * 128 + kc * 32 + quad * 8;
      const float4 q1 = *(const float4*)(Wq + off);
      const float4 q2 = *(const float4*)(Wq + off + 4);
      const float4 k1 = *(const float4*)(Wk + off);
      const float4 k2 = *(const float4*)(Wk + off + 4);
      union { uint4 u; bf16x8 v; } cq, ck;
      cq.u.x = pk2bf(q1.x * INV_SCALE, q1.y * INV_SCALE);
      cq.u.y = pk2bf(q1.z * INV_SCALE, q1.w * INV_SCALE);
      cq.u.z = pk2bf(q2.x * INV_SCALE, q2.y * INV_SCALE);
      cq.u.w = pk2bf(q2.z * INV_SCALE, q2.w * INV_SCALE);
      ck.u.x = pk2bf(k1.x, k1.y);
      ck.u.y = pk2bf(k1.z, k1.w);
      ck.u.z = pk2bf(k2.x, k2.y);
      ck.u.w = pk2bf(k2.z, k2.w);
      aq[ot][kc] = cq.v;
      ak[ot][kc] = ck.v;
    }
  __syncthreads();

#pragma unroll
  for (int jtl = 0; jtl < 4; ++jtl) {
    bf16x8 bfr[4];
#pragma unroll
    for (int kc = 0; kc < 4; ++kc) {
      const float* sp = xl + (kc * 32 + quad * 8) * 66 + jtl * 16 + lm;
      float f0 = sp[0],   f1 = sp[66],  f2 = sp[132], f3 = sp[198];
      float f4 = sp[264], f5 = sp[330], f6 = sp[396], f7 = sp[462];
      union { uint4 u; bf16x8 v; } cv;
      cv.u.x = pkfast(f0, f1);
      cv.u.y = pkfast(f2, f3);
      cv.u.z = pkfast(f4, f5);
      cv.u.w = pkfast(f6, f7);
      bfr[kc] = cv.v;
    }

    f32x4 accq0 = {0,0,0,0}, accq1 = {0,0,0,0};
    f32x4 acck0 = {0,0,0,0}, acck1 = {0,0,0,0};
#pragma unroll
    for (int kc = 0; kc < 4; ++kc) {
      accq0 = __builtin_amdgcn_mfma_f32_16x16x32_bf16(aq[0][kc], bfr[kc], accq0, 0, 0, 0);
      accq1 = __builtin_amdgcn_mfma_f32_16x16x32_bf16(aq[1][kc], bfr[kc], accq1, 0, 0, 0);
      acck0 = __builtin_amdgcn_mfma_f32_16x16x32_bf16(ak[0][kc], bfr[kc], acck0, 0, 0, 0);
      acck1 = __builtin_amdgcn_mfma_f32_16x16x32_bf16(ak[1][kc], bfr[kc], acck1, 0, 0, 0);
    }

    const size_t base = (size_t)b * 1048576 + (size_t)lm * 65536 + w * 16384 +
                        (size_t)(nq + jtl) * 32 + quad * 4;
    uint2 uq0, uq1, uk0, uk1;
    uq0.x = pk2bf(accq0[0], accq0[1]); uq0.y = pk2bf(accq0[2], accq0[3]);
    uq1.x = pk2bf(accq1[0], accq1[1]); uq1.y = pk2bf(accq1[2], accq1[3]);
    uk0.x = pk2bf(acck0[0], acck0[1]); uk0.y = pk2bf(acck0[2], acck0[3]);
    uk1.x = pk2bf(acck1[0], acck1[1]); uk1.y = pk2bf(acck1[2], acck1[3]);
    *(uint2*)(Qb + base)      = uq0;
    *(uint2*)(Qb + base + 16) = uq1;
    *(uint2*)(Kb + base)      = uk0;
    *(uint2*)(Kb + base + 16) = uk1;
  }

  // structural softmax, row i = bid
  {
    float* red = (float*)(smem + 34816);
    __syncthreads();
    const int i = bid;
    float s0 = S[i * 512 + tid], s1 = S[i * 512 + tid + 256];
    float m = blk_max(fmaxf(s0, s1), red, tid);
    float e0 = __expf(s0 - m), e1 = __expf(s1 - m);
    float sum = blk_sum(e0 + e1, red, tid);
    float inv = 1.0f / sum;
    st[i * 512 + tid] = e0 * inv;
    st[i * 512 + tid + 256] = e1 * inv;
  }
}

// ---------------------------------------------------------------------------
// Dispatch 2: MFMA scores + softmax + partial mean over (t,h).
// Grid (32 strips, GPART=8, 4 b), 256 threads (4 waves).
// ---------------------------------------------------------------------------
__global__ __launch_bounds__(256, 4) void k_ph2(const ushort* __restrict__ Qb,
                                                const ushort* __restrict__ Kb,
                                                ushort* __restrict__ part) {
  __shared__ float SH[16 * 516];   // epilogue transpose only
  __shared__ float red[2][4][16];  // [pair parity][wave][row]
  const int strip = blockIdx.x, g = blockIdx.y, b = blockIdx.z;
  const int tid = threadIdx.x;
  const int w = tid >> 6, lane = tid & 63;
  const int lm = lane & 15, quad = lane >> 4;
  const int n0 = strip * 16;
  const int wcol0 = w * 128;

  float acc[32];
#pragma unroll
  for (int i = 0; i < 32; ++i) acc[i] = 0.f;

  for (int pi = 0; pi < 8; ++pi) {
    const int p = (g << 3) + pi;
    const size_t base = (size_t)((b * 16 + (p >> 2)) * 4 + (p & 3)) * 16384;
    bf16x8 afrag = *(const bf16x8*)(Qb + base + (size_t)(n0 + lm) * 32 + quad * 8);
    bf16x8 bfr[8];
#pragma unroll
    for (int ct = 0; ct < 8; ++ct)
      bfr[ct] = *(const bf16x8*)(Kb + base + (size_t)(wcol0 + ct * 16 + lm) * 32 + quad * 8);

    f32x4 d[8];
#pragma unroll
    for (int ct = 0; ct < 8; ++ct) {
      f32x4 z = {0.f, 0.f, 0.f, 0.f};
      d[ct] = __builtin_amdgcn_mfma_f32_16x16x32_bf16(afrag, bfr[ct], z, 0, 0, 0);
    }

    float cur[32];
    float rp0 = 0.f, rp1 = 0.f, rp2 = 0.f, rp3 = 0.f;
#pragma unroll
    for (int ct = 0; ct < 8; ++ct) {
      float e0 = __expf(d[ct][0]);
      float e1 = __expf(d[ct][1]);
      float e2 = __expf(d[ct][2]);
      float e3 = __expf(d[ct][3]);
      cur[ct * 4 + 0] = e0; cur[ct * 4 + 1] = e1;
      cur[ct * 4 + 2] = e2; cur[ct * 4 + 3] = e3;
      rp0 += e0; rp1 += e1; rp2 += e2; rp3 += e3;
    }
#pragma unroll
    for (int m = 1; m < 16; m <<= 1) {
      rp0 += __shfl_xor(rp0, m);
      rp1 += __shfl_xor(rp1, m);
      rp2 += __shfl_xor(rp2, m);
      rp3 += __shfl_xor(rp3, m);
    }
    if (lm == 0) {
      red[pi & 1][w][quad * 4 + 0] = rp0;
      red[pi & 1][w][quad * 4 + 1] = rp1;
      red[pi & 1][w][quad * 4 + 2] = rp2;
      red[pi & 1][w][quad * 4 + 3] = rp3;
    }
    __syncthreads();
#pragma unroll
    for (int r = 0; r < 4; ++r) {
      float rs = red[pi & 1][0][quad * 4 + r] + red[pi & 1][1][quad * 4 + r] +
                 red[pi & 1][2][quad * 4 + r] + red[pi & 1][3][quad * 4 + r];
      float inv = 1.0f / rs;
#pragma unroll
      for (int ct = 0; ct < 8; ++ct)
        acc[ct * 4 + r] = fmaf(cur[ct * 4 + r], inv, acc[ct * 4 + r]);
    }
  }

#pragma unroll
  for (int ct = 0; ct < 8; ++ct) {
#pragma unroll
    for (int r = 0; r < 4; ++r)
      SH[(quad * 4 + r) * 516 + wcol0 + ct * 16 + lm] = acc[ct * 4 + r];
  }
  __syncthreads();
  const int row = tid >> 4, colb = (tid & 15) * 4;
  ushort* po = part + ((size_t)((g * 4 + b) * 512 + n0 + row)) * 512 + colb;
#pragma unroll
  for (int k = 0; k < 8; ++k) {
    f32x4 v = *(const f32x4*)(SH + row * 516 + colb + k * 64);
    uint2 u;
    u.x = pk2bf(v[0], v[1]);
    u.y = pk2bf(v[2], v[3]);
    *(uint2*)(po + k * 64) = u;
  }
}

// ---------------------------------------------------------------------------
// Dispatch 3: xconv (all 512 blocks) + redsym (blocks 0..179).
// xconv: x[b,c,j,t] fp32 -> xtb[b,c,t,j] bf16  (bid -> c=bid&127, b=bid>>7)
// redsym: z = bid/36 (0..3 accA-b, 4 = st in place), tile-pair = bid%36.
// ---------------------------------------------------------------------------
__global__ __launch_bounds__(256) void k_ph3(const float* __restrict__ x,
                                             ushort* __restrict__ xtb,
                                             const ushort* __restrict__ part,
                                             float* __restrict__ Ssym,
                                             float* __restrict__ st) {
  __shared__ __align__(16) char smem[SMEM_SZ];
  const int bid = blockIdx.x;
  const int tid = threadIdx.x;

  // --- xconv ---
  {
    ushort* xs = (ushort*)smem;  // 16*520*2 = 16640 B
    const int c = bid & 127, b = bid >> 7;
    const float* in = x + ((size_t)b * 128 + c) * 8192;
    ushort* outp = xtb + ((size_t)b * 128 + c) * 8192;
#pragma unroll
    for (int it = 0; it < 8; ++it) {
      int idx = (tid + it * 256) * 4;
      int j = idx >> 4, t0 = idx & 15;
      float4 v = *(const float4*)(in + idx);
      xs[(t0 + 0) * 520 + j] = cv1(v.x);
      xs[(t0 + 1) * 520 + j] = cv1(v.y);
      xs[(t0 + 2) * 520 + j] = cv1(v.z);
      xs[(t0 + 3) * 520 + j] = cv1(v.w);
    }
    __syncthreads();
#pragma unroll
    for (int it = 0; it < 4; ++it) {
      int u = (tid + it * 256) * 8;
      int t = u >> 9, j0 = u & 511;
      *(uint4*)(outp + u) = *(const uint4*)(xs + t * 520 + j0);
    }
  }
  __syncthreads();

  // --- redsym (first 180 blocks) ---
  if (bid < 180) {
    float* L1 = (float*)smem;        // 17408 B
    float* L2 = L1 + 64 * 68;        // 17408 B
    const int z = bid / 36;
    int rem = bid % 36, ti = 0;
    for (;;) { int cnt = 8 - ti; if (rem < cnt) break; rem -= cnt; ++ti; }
    const int tj = ti + rem;
    const bool diag = (ti == tj);
    const int rr = tid >> 2, cc = (tid & 3) * 16;

    float a1[16], a2[16];
#pragma unroll
    for (int k = 0; k < 16; ++k) { a1[k] = 0.f; a2[k] = 0.f; }

    if (z == 4) {
      const float* p1 = st + (ti * 64 + rr) * 512 + tj * 64 + cc;
      const float* p2 = st + (tj * 64 + rr) * 512 + ti * 64 + cc;
#pragma unroll
      for (int q = 0; q < 4; ++q) {
        float4 v = *(const float4*)(p1 + q * 4);
        a1[q * 4 + 0] = v.x; a1[q * 4 + 1] = v.y;
        a1[q * 4 + 2] = v.z; a1[q * 4 + 3] = v.w;
        if (!diag) {
          float4 u = *(const float4*)(p2 + q * 4);
          a2[q * 4 + 0] = u.x; a2[q * 4 + 1] = u.y;
          a2[q * 4 + 2] = u.z; a2[q * 4 + 3] = u.w;
        }
      }
    } else {
      const int b = z;
#pragma unroll
      for (int g = 0; g < GPART; ++g) {
        const ushort* p1 = part + ((size_t)((g * 4 + b) * 512 + ti * 64 + rr)) * 512 + tj * 64 + cc;
        const ushort* p2 = part + ((size_t)((g * 4 + b) * 512 + tj * 64 + rr)) * 512 + ti * 64 + cc;
#pragma unroll
        for (int q = 0; q < 4; ++q) {
          ushort4 v = *(const ushort4*)(p1 + q * 4);
          a1[q * 4 + 0] += bf2f(v.x); a1[q * 4 + 1] += bf2f(v.y);
          a1[q * 4 + 2] += bf2f(v.z); a1[q * 4 + 3] += bf2f(v.w);
          if (!diag) {
            ushort4 u = *(const ushort4*)(p2 + q * 4);
            a2[q * 4 + 0] += bf2f(u.x); a2[q * 4 + 1] += bf2f(u.y);
            a2[q * 4 + 2] += bf2f(u.z); a2[q * 4 + 3] += bf2f(u.w);
          }
        }
      }
    }

#pragma unroll
    for (int q = 0; q < 4; ++q) {
      *(float4*)(L1 + rr * 68 + cc + q * 4) =
          make_float4(a1[q * 4], a1[q * 4 + 1], a1[q * 4 + 2], a1[q * 4 + 3]);
      if (!diag)
        *(float4*)(L2 + rr * 68 + cc + q * 4) =
            make_float4(a2[q * 4], a2[q * 4 + 1], a2[q * 4 + 2], a2[q * 4 + 3]);
    }
    __syncthreads();

    float* M = (z < 4) ? (Ssym + (size_t)z * 262144) : st;
    const float* LT = diag ? L1 : L2;
#pragma unroll
    for (int q = 0; q < 4; ++q) {
      const int c = cc + q * 4;
      float4 o;
      o.x = L1[rr * 68 + c + 0] + LT[(c + 0) * 68 + rr];
      o.y = L1[rr * 68 + c + 1] + LT[(c + 1) * 68 + rr];
      o.z = L1[rr * 68 + c + 2] + LT[(c + 2) * 68 + rr];
      o.w = L1[rr * 68 + c + 3] + LT[(c + 3) * 68 + rr];
      *(float4*)(M + (ti * 64 + rr) * 512 + tj * 64 + c) = o;
    }
    if (!diag) {
#pragma unroll
      for (int q = 0; q < 4; ++q) {
        const int c = cc + q * 4;
        float4 o;
        o.x = L2[rr * 68 + c + 0] + L1[(c + 0) * 68 + rr];
        o.y = L2[rr * 68 + c + 1] + L1[(c + 1) * 68 + rr];
        o.z = L2[rr * 68 + c + 2] + L1[(c + 2) * 68 + rr];
        o.w = L2[rr * 68 + c + 3] + L1[(c + 3) * 68 + rr];
        *(float4*)(M + (tj * 64 + rr) * 512 + ti * 64 + c) = o;
      }
    }
  }
}

// ---------------------------------------------------------------------------
// Dispatch 4: fused row softmax -> bf16. bid = i; loop over b in-kernel.
// ---------------------------------------------------------------------------
__global__ __launch_bounds__(256) void k_ph4(const float* __restrict__ Ssym,
                                             const float* __restrict__ st,
                                             const float* __restrict__ fw,
                                             const float* __restrict__ fb,
                                             ushort* __restrict__ fusedb) {
  __shared__ float red[4];
  const int i = blockIdx.x, tid = threadIdx.x;
  const float w0s = fw[0] * (0.5f / 64.f);
  const float w1s = fw[1] * 0.5f;
  const float bias = fb[0];
  float2 s2 = *(const float2*)(st + (size_t)i * 512 + tid * 2);
  for (int b = 0; b < 4; ++b) {
    const float* A = Ssym + (size_t)b * 262144 + (size_t)i * 512;
    float2 a2 = *(const float2*)(A + tid * 2);
    float l0 = fmaf(w0s, a2.x, fmaf(w1s, s2.x, bias));
    float l1 = fmaf(w0s, a2.y, fmaf(w1s, s2.y, bias));
    float m = blk_max(fmaxf(l0, l1), red, tid);
    float e0 = __expf(l0 - m), e1 = __expf(l1 - m);
    float sum = blk_sum(e0 + e1, red, tid);
    float inv = 1.0f / sum;
    *(unsigned int*)(fusedb + ((size_t)(b * 512 + i)) * 512 + tid * 2) =
        pk2bf(e0 * inv, e1 * inv);
  }
}

// ---------------------------------------------------------------------------
// Dispatch 5: MFMA aggregation. out[b,c,i,t] = sum_j fusedb[b,i,j]*xtb[b,c,t,j]
// ---------------------------------------------------------------------------
__global__ __launch_bounds__(256) void k_ph5(const ushort* __restrict__ fusedb,
                                             const ushort* __restrict__ xtb,
                                             float* __restrict__ out) {
  __shared__ ushort xs[16 * 520];
  const int cg = blockIdx.x;
  const int i0 = blockIdx.y * 64;
  const int b = blockIdx.z;
  const int tid = threadIdx.x, w = tid >> 6, lane = tid & 63;
  const int lm = lane & 15, quad = lane >> 4;

  const ushort* fr = fusedb + ((size_t)(b * 512 + i0 + w * 16 + lm)) * 512 + quad * 8;
  bf16x8 af[16];
#pragma unroll
  for (int kk = 0; kk < 16; ++kk) af[kk] = *(const bf16x8*)(fr + kk * 32);

  const ushort* xg = xtb + ((size_t)b * 128 + cg * 8) * 8192;
  uint4 rg[4];
#pragma unroll
  for (int it = 0; it < 4; ++it) rg[it] = *(const uint4*)(xg + (tid + it * 256) * 8);

  for (int c = 0; c < 8; ++c) {
#pragma unroll
    for (int it = 0; it < 4; ++it) {
      int u = (tid + it * 256) * 8;
      int t = u >> 9, j0 = u & 511;
      *(uint4*)(xs + t * 520 + j0) = rg[it];
    }
    __syncthreads();
    if (c < 7) {
      const ushort* xg2 = xg + (size_t)(c + 1) * 8192;
#pragma unroll
      for (int it = 0; it < 4; ++it) rg[it] = *(const uint4*)(xg2 + (tid + it * 256) * 8);
    }
    f32x4 acc = {0.f, 0.f, 0.f, 0.f};
#pragma unroll
    for (int kk = 0; kk < 16; ++kk) {
      bf16x8 bf = *(const bf16x8*)(xs + lm * 520 + kk * 32 + quad * 8);
      acc = __builtin_amdgcn_mfma_f32_16x16x32_bf16(af[kk], bf, acc, 0, 0, 0);
    }
    float* op = out + (size_t)b * 1048576 + (size_t)(cg * 8 + c) * 8192 +
                (size_t)(i0 + w * 16 + quad * 4) * 16 + lm;
    op[0]  = acc[0];
    op[16] = acc[1];
    op[32] = acc[2];
    op[48] = acc[3];
    __syncthreads();
  }
}

// ---------------------------------------------------------------------------
extern "C" void kernel_launch(void* const* d_in, const int* in_sizes, int n_in,
                              void* d_out, int out_size, void* d_ws, size_t ws_size,
                              hipStream_t stream) {
  const float* x  = (const float*)d_in[0];
  const float* Wq = (const float*)d_in[1];
  const float* Wk = (const float*)d_in[2];
  const float* S  = (const float*)d_in[3];
  const float* fw = (const float*)d_in[4];
  const float* fb = (const float*)d_in[5];
  float* out = (float*)d_out;

  // workspace (39 MB): Qb 8 | Kb 8 | part 16 | Ssym 4 | st 1 | fusedb 2
  // xtb overlays Qb (written in dispatch 3, after Qb's last read in dispatch 2)
  ushort* Qb   = (ushort*)d_ws;
  ushort* Kb   = Qb + 4194304;
  ushort* part = Kb + 4194304;     // GPART(8) x 4 b x 512 x 512 bf16 = 16 MB
  ushort* xtb  = Qb;               // overlay
  float* Ssym  = (float*)(part + 8388608);
  float* st    = Ssym + 1048576;
  ushort* fusedb = (ushort*)(st + 262144);

  k_ph1<<<dim3(512),          256, 0, stream>>>(x, Wq, Wk, S, Qb, Kb, st);
  k_ph2<<<dim3(32, GPART, 4), 256, 0, stream>>>(Qb, Kb, part);
  k_ph3<<<dim3(512),          256, 0, stream>>>(x, xtb, part, Ssym, st);
  k_ph4<<<dim3(512),          256, 0, stream>>>(Ssym, st, fw, fb, fusedb);
  k_ph5<<<dim3(16, 8, 4),     256, 0, stream>>>(fusedb, xtb, out);
}